// Round 8
// baseline (173.885 us; speedup 1.0000x reference)
//
#include <hip/hip_runtime.h>

// B=32, T=2048, E=128, fp32. Gram restructure, v6 (launch-count cut):
//   R7 accounting: ~10us launch/gap overhead per dispatch (R6: kernels 124us
//   visible vs 183 wall) -> merge KB+KC+KD into ONE kernel kf_cet (B,2):
//   sx reduce + c from M partials (L2-resident) + et = xw + c.U + softmax,
//   all in-block, et softmaxed in registers (KD's ws re-read deleted).
//   Launches: KA, KF, KE (+harness fill).
//   KA: MFMA split-bf16 Gram (R7, passed) unchanged. KE unchanged.

#define B_ 32
#define T_ 2048
#define E_ 128
#define EV (E_/4)
#define INV_T (1.0f/2048.0f)
#define RC 128      // rows per KA block
#define NG (T_/RC)  // 16 chunks

#define WS_PSX1 0                      // B*NG*E = 65536
#define WS_PSX2 65536                  // B*NG*E
#define WS_PM   131072                 // B*NG*E*E = 8388608 (33.5MB)
#define WS_ET1  8519680                // B*T
#define WS_ET2  8585216                // B*T

typedef __attribute__((ext_vector_type(8))) short short8;
typedef __attribute__((ext_vector_type(4))) float f32x4;

__device__ __forceinline__ float dot4(float4 a, float4 b) {
    return a.x*b.x + a.y*b.y + a.z*b.z + a.w*b.w;
}
__device__ __forceinline__ void fma4(float4& a, float s, const float4 v) {
    a.x += s*v.x; a.y += s*v.y; a.z += s*v.z; a.w += s*v.w;
}
__device__ __forceinline__ void add4(float4& a, const float4 v) {
    a.x += v.x; a.y += v.y; a.z += v.z; a.w += v.w;
}

__device__ __forceinline__ unsigned swz(int e, unsigned tbyte) {
    return tbyte ^ ((((unsigned)e & 3u) << 3) | ((((unsigned)e >> 2) & 3u) << 5));
}

// pack 4 consecutive-t fp32 for one e-row into hi/lo bf16 pair-words
__device__ __forceinline__ void pack_hilo(float f0, float f1, float f2, float f3,
                                          unsigned long long& wh,
                                          unsigned long long& wl) {
    unsigned u0 = __float_as_uint(f0), u1 = __float_as_uint(f1);
    unsigned u2 = __float_as_uint(f2), u3 = __float_as_uint(f3);
    unsigned h0 = u0 & 0xFFFF0000u, h1 = u1 & 0xFFFF0000u;
    unsigned h2 = u2 & 0xFFFF0000u, h3 = u3 & 0xFFFF0000u;
    unsigned hw0 = h1 | (h0 >> 16);
    unsigned hw1 = h3 | (h2 >> 16);
    unsigned l0 = __float_as_uint(f0 - __uint_as_float(h0));
    unsigned l1 = __float_as_uint(f1 - __uint_as_float(h1));
    unsigned l2 = __float_as_uint(f2 - __uint_as_float(h2));
    unsigned l3 = __float_as_uint(f3 - __uint_as_float(h3));
    unsigned lw0 = (l1 & 0xFFFF0000u) | (l0 >> 16);
    unsigned lw1 = (l3 & 0xFFFF0000u) | (l2 >> 16);
    wh = ((unsigned long long)hw1 << 32) | hw0;
    wl = ((unsigned long long)lw1 << 32) | lw0;
}

__device__ __forceinline__ short8 frag_ld(const char* buf, int row, int t0) {
    unsigned a1 = (unsigned)row * 128u + swz(row, (unsigned)t0 * 2u);
    union { unsigned long long u[2]; short8 v; } r;
    r.u[0] = *(const unsigned long long*)(buf + a1);
    r.u[1] = *(const unsigned long long*)(buf + (a1 ^ 32u));  // t0+16 block
    return r.v;
}

// ---- KA: Gram (MFMA split-bf16) + psx partial + xw logit base, one x pass ----
__global__ __launch_bounds__(256)
void ka_gram(const float* __restrict__ x1, const float* __restrict__ x2,
             const float* __restrict__ W1, const float* __restrict__ b1,
             const float* __restrict__ W2, const float* __restrict__ b2,
             float* __restrict__ ws) {
    __shared__ unsigned short ldsq[4][128][64];   // h1,l1,h2,l2 : 64 KB
    __shared__ float4 sW[2][32];
    const int b = blockIdx.x, g = blockIdx.y, tid = threadIdx.x;
    if (tid < 64) sW[tid>>5][tid&31] = ((const float4*)((tid<32) ? W1 : W2))[tid&31];
    __syncthreads();   // sW visible before first xw dot (R2 lesson)

    const int eq = tid & 31, tp = tid >> 5;       // staging role
    const int lane = tid & 63, w = tid >> 6;      // MFMA role: wave w owns e 32w..32w+31

    const float4* x1g = (const float4*)x1 + ((size_t)b*T_ + g*RC)*EV;
    const float4* x2g = (const float4*)x2 + ((size_t)b*T_ + g*RC)*EV;

    float4 psA1 = {0,0,0,0}, psA2 = {0,0,0,0};
    f32x4 acc[2][8];
    #pragma unroll
    for (int i = 0; i < 2; ++i)
        #pragma unroll
        for (int j = 0; j < 8; ++j) acc[i][j] = (f32x4){0.f,0.f,0.f,0.f};

    char* Lb = (char*)&ldsq[0][0][0];
    const char* Apass[3] = { Lb + 2*16384, Lb + 2*16384, Lb + 3*16384 };  // h2,h2,l2
    const char* Bpass[3] = { Lb + 0,       Lb + 1*16384, Lb + 0       };  // h1,l1,h1

    for (int s = 0; s < 2; ++s) {
        // ---- stage 64 t-rows of both tensors (fp32 -> hi/lo bf16, transposed) ----
        #pragma unroll
        for (int u = 0; u < 4; ++u) {
            const int ten = u >> 1;
            const int tq  = tp + (u & 1)*8;       // 0..15 t-quad within stage
            const int tl  = tq*4;                 // local t (0..63)
            const int tr  = s*64 + tl;            // t within chunk (0..127)
            const float4* src = (ten ? x2g : x1g) + (size_t)tr*EV + eq;
            const float4 v0 = src[0], v1 = src[EV], v2 = src[2*EV], v3 = src[3*EV];
            float4& ps = ten ? psA2 : psA1;
            add4(ps, v0); add4(ps, v1); add4(ps, v2); add4(ps, v3);
            const float4 wv = sW[ten][eq];
            float d0 = dot4(v0,wv), d1 = dot4(v1,wv), d2 = dot4(v2,wv), d3 = dot4(v3,wv);
            #pragma unroll
            for (int mm = 1; mm <= 16; mm <<= 1) {
                d0 += __shfl_xor(d0, mm); d1 += __shfl_xor(d1, mm);
                d2 += __shfl_xor(d2, mm); d3 += __shfl_xor(d3, mm);
            }
            if (eq == 0) {
                const int tg = g*RC + tr;
                const float4 bb = *(const float4*)((ten ? b2 : b1) + tg);
                *(float4*)(ws + (ten ? WS_ET2 : WS_ET1) + (size_t)b*T_ + tg)
                    = make_float4(d0+bb.x, d1+bb.y, d2+bb.z, d3+bb.w);
            }
            char* Hb = Lb + (ten ? 2 : 0)*16384;
            char* Lo = Hb + 16384;
            const unsigned tb = (unsigned)tl * 2u;
            unsigned long long wh, wl;
            {   const int e = eq*4 + 0; const unsigned off = (unsigned)e*128u + swz(e, tb);
                pack_hilo(v0.x, v1.x, v2.x, v3.x, wh, wl);
                *(unsigned long long*)(Hb + off) = wh;
                *(unsigned long long*)(Lo + off) = wl; }
            {   const int e = eq*4 + 1; const unsigned off = (unsigned)e*128u + swz(e, tb);
                pack_hilo(v0.y, v1.y, v2.y, v3.y, wh, wl);
                *(unsigned long long*)(Hb + off) = wh;
                *(unsigned long long*)(Lo + off) = wl; }
            {   const int e = eq*4 + 2; const unsigned off = (unsigned)e*128u + swz(e, tb);
                pack_hilo(v0.z, v1.z, v2.z, v3.z, wh, wl);
                *(unsigned long long*)(Hb + off) = wh;
                *(unsigned long long*)(Lo + off) = wl; }
            {   const int e = eq*4 + 3; const unsigned off = (unsigned)e*128u + swz(e, tb);
                pack_hilo(v0.w, v1.w, v2.w, v3.w, wh, wl);
                *(unsigned long long*)(Hb + off) = wh;
                *(unsigned long long*)(Lo + off) = wl; }
        }
        __syncthreads();
        // ---- MFMA: 3 passes x 2 k-steps; wave w: e-tiles {2w,2w+1}, f-tiles 0..7 ----
        #pragma unroll
        for (int pass = 0; pass < 3; ++pass) {
            #pragma unroll
            for (int ks = 0; ks < 2; ++ks) {
                const int t0 = ks*32 + ((lane>>4)<<2);
                const short8 a0 = frag_ld(Apass[pass], w*32 + (lane&15), t0);
                const short8 a1 = frag_ld(Apass[pass], w*32 + 16 + (lane&15), t0);
                #pragma unroll
                for (int ft = 0; ft < 8; ++ft) {
                    const short8 bv = frag_ld(Bpass[pass], ft*16 + (lane&15), t0);
                    acc[0][ft] = __builtin_amdgcn_mfma_f32_16x16x32_bf16(a0, bv, acc[0][ft], 0, 0, 0);
                    acc[1][ft] = __builtin_amdgcn_mfma_f32_16x16x32_bf16(a1, bv, acc[1][ft], 0, 0, 0);
                }
            }
        }
        __syncthreads();
    }

    // ---- M partial write: D layout col=lane&15 (=f), row=(lane>>4)*4+r (=e) [m89] ----
    float* pM = ws + WS_PM + (size_t)(b*NG + g)*16384;
    #pragma unroll
    for (int et = 0; et < 2; ++et) {
        #pragma unroll
        for (int ft = 0; ft < 8; ++ft) {
            #pragma unroll
            for (int r = 0; r < 4; ++r) {
                const int e = w*32 + et*16 + ((lane>>4)<<2) + r;
                const int f = ft*16 + (lane&15);
                pM[e*128 + f] = acc[et][ft][r];
            }
        }
    }

    // ---- psx partial: reduce 8 tp-owners per (tensor, e-quad); ldsq is dead ----
    float4* spx = (float4*)Lb;
    spx[tid*2 + 0] = psA1; spx[tid*2 + 1] = psA2;
    __syncthreads();
    if (tid < 64) {
        const int ten = tid>>5, eqq = tid&31;
        float4 sum = {0,0,0,0};
        #pragma unroll
        for (int t2 = 0; t2 < 8; ++t2) add4(sum, spx[(t2*32 + eqq)*2 + ten]);
        ((float4*)(ws + (ten ? WS_PSX2 : WS_PSX1)))[(size_t)(b*NG + g)*32 + eqq] = sum;
    }
}

// ---- KF: merged KB+KC+KD. grid (B,2), 512 thr.
//   sel=0: c1 = M.sx2/T;  sel=1: c2 = M^T.sx1/T   (M partials L2-resident)
//   then et = xw_base + c.U (U L2-resident), softmax in registers, probs->ws ----
__global__ __launch_bounds__(512)
void kf_cet(const float* __restrict__ U1, const float* __restrict__ U2,
            float* __restrict__ ws, float* __restrict__ out) {
    __shared__ float ssx[E_];
    __shared__ float s_c[E_];
    __shared__ float4 c2p[16][32];
    __shared__ float red[512];
    const int b = blockIdx.x, sel = blockIdx.y, tid = threadIdx.x;
    if (tid < 128) {
        const float* ps = ws + (sel ? WS_PSX1 : WS_PSX2);  // c1 needs sx2, c2 needs sx1
        float s = 0.f;
        #pragma unroll
        for (int g = 0; g < NG; ++g) s += ps[(size_t)(b*NG + g)*E_ + tid];
        ssx[tid] = s;
    }
    __syncthreads();
    const float4* pM4 = (const float4*)(ws + WS_PM) + (size_t)b*NG*4096;
    const float4* sx4 = (const float4*)ssx;
    if (sel == 0) {
        // c1[e]: e = tid>>2, part = tid&3 covers f4 part*8..part*8+7
        const int e = tid >> 2, part = tid & 3;
        float ca = 0.f;
        for (int g = 0; g < NG; ++g) {
            #pragma unroll
            for (int i = 0; i < 8; ++i)
                ca += dot4(pM4[(size_t)g*4096 + e*32 + part*8 + i], sx4[part*8 + i]);
        }
        ca += __shfl_xor(ca, 1); ca += __shfl_xor(ca, 2);
        if (part == 0) s_c[e] = ca * INV_T;
    } else {
        // c2[f]: eg = tid>>5 (16 groups of 8 e), f4 = tid&31
        const int eg = tid >> 5, f4 = tid & 31;
        float4 a = {0,0,0,0};
        for (int g = 0; g < NG; ++g) {
            #pragma unroll
            for (int i = 0; i < 8; ++i) {
                const int e = eg*8 + i;
                fma4(a, ssx[e], pM4[(size_t)g*4096 + e*32 + f4]);
            }
        }
        c2p[eg][f4] = a;
        __syncthreads();
        if (tid < 128) {
            const int qr = tid >> 5, f = tid & 31;
            float4 s = {0,0,0,0};
            #pragma unroll
            for (int j = 0; j < 4; ++j) add4(s, c2p[qr*4 + j][f]);
            c2p[qr][f] = s;
        }
        __syncthreads();
        if (tid < 32) {
            float4 s = {0,0,0,0};
            #pragma unroll
            for (int j = 0; j < 4; ++j) add4(s, c2p[j][tid]);
            s.x *= INV_T; s.y *= INV_T; s.z *= INV_T; s.w *= INV_T;
            ((float4*)s_c)[tid] = s;
        }
    }
    __syncthreads();

    // et = xw_base + c.U  (tid owns t4 = tid, i.e. t = 4*tid..4*tid+3)
    const float4* U4 = (const float4*)(sel ? U2 : U1);   // E x T/4
    float4* et4 = (float4*)(ws + (sel ? WS_ET2 : WS_ET1) + (size_t)b*T_);
    float4 accA = et4[tid];
    float4 accB = {0,0,0,0}, accC = {0,0,0,0}, accD = {0,0,0,0};
    #pragma unroll 2
    for (int e = 0; e < E_; e += 4) {
        fma4(accA, s_c[e+0], U4[(size_t)(e+0)*(T_/4) + tid]);
        fma4(accB, s_c[e+1], U4[(size_t)(e+1)*(T_/4) + tid]);
        fma4(accC, s_c[e+2], U4[(size_t)(e+2)*(T_/4) + tid]);
        fma4(accD, s_c[e+3], U4[(size_t)(e+3)*(T_/4) + tid]);
    }
    add4(accA, accB); add4(accC, accD); add4(accA, accC);
    if (tid < E_) out[b*2*E_ + sel*E_ + tid] = 0.f;

    // softmax over the 2048 logits held in registers
    float m = fmaxf(fmaxf(accA.x, accA.y), fmaxf(accA.z, accA.w));
    red[tid] = m; __syncthreads();
    for (int s = 256; s > 0; s >>= 1) {
        if (tid < s) red[tid] = fmaxf(red[tid], red[tid+s]);
        __syncthreads();
    }
    m = red[0]; __syncthreads();
    float4 e4;
    e4.x = __expf(accA.x - m); e4.y = __expf(accA.y - m);
    e4.z = __expf(accA.z - m); e4.w = __expf(accA.w - m);
    red[tid] = e4.x + e4.y + e4.z + e4.w;
    __syncthreads();
    for (int s = 256; s > 0; s >>= 1) {
        if (tid < s) red[tid] += red[tid+s];
        __syncthreads();
    }
    const float il = 1.f / red[0];
    e4.x *= il; e4.y *= il; e4.z *= il; e4.w *= il;
    et4[tid] = e4;                        // probs for KE
}

// ---- KE: o = sum_t at[t]*x[t,:] (proven) ----
__global__ __launch_bounds__(256)
void ke_out(const float* __restrict__ x1, const float* __restrict__ x2,
            const float* __restrict__ ws, float* __restrict__ out) {
    __shared__ float4 s_r1[256], s_r2[256];
    __shared__ float s_p1[128], s_p2[128];
    const int b = blockIdx.x, g = blockIdx.y, tid = threadIdx.x;
    const float* pr1 = ws + WS_ET1 + (size_t)b*T_ + g*128;
    const float* pr2 = ws + WS_ET2 + (size_t)b*T_ + g*128;
    if (tid < 128) s_p1[tid] = pr1[tid];
    else           s_p2[tid - 128] = pr2[tid - 128];
    __syncthreads();
    const float4* p1 = (const float4*)x1 + ((size_t)b*T_ + g*128)*EV;
    const float4* p2 = (const float4*)x2 + ((size_t)b*T_ + g*128)*EV;
    const int rg = tid >> 5, q = tid & 31;
    float4 a1 = {0,0,0,0}, a2 = {0,0,0,0};
    #pragma unroll
    for (int i = 0; i < 16; ++i) {
        int r = i*8 + rg;
        fma4(a1, s_p1[r], p1[r*EV + q]);
        fma4(a2, s_p2[r], p2[r*EV + q]);
    }
    s_r1[tid] = a1; s_r2[tid] = a2;
    __syncthreads();
    for (int s = 128; s >= 32; s >>= 1) {
        if (tid < s) { add4(s_r1[tid], s_r1[tid+s]); add4(s_r2[tid], s_r2[tid+s]); }
        __syncthreads();
    }
    if (tid < 32) {
        float4 t1 = s_r1[tid], t2 = s_r2[tid];
        atomicAdd(&out[b*2*E_ + tid*4+0], t1.x);
        atomicAdd(&out[b*2*E_ + tid*4+1], t1.y);
        atomicAdd(&out[b*2*E_ + tid*4+2], t1.z);
        atomicAdd(&out[b*2*E_ + tid*4+3], t1.w);
        atomicAdd(&out[b*2*E_ + E_ + tid*4+0], t2.x);
        atomicAdd(&out[b*2*E_ + E_ + tid*4+1], t2.y);
        atomicAdd(&out[b*2*E_ + E_ + tid*4+2], t2.z);
        atomicAdd(&out[b*2*E_ + E_ + tid*4+3], t2.w);
    }
}

extern "C" void kernel_launch(void* const* d_in, const int* in_sizes, int n_in,
                              void* d_out, int out_size, void* d_ws, size_t ws_size,
                              hipStream_t stream) {
    const float* x1 = (const float*)d_in[0];
    const float* x2 = (const float*)d_in[1];
    const float* W1 = (const float*)d_in[2];
    const float* b1 = (const float*)d_in[3];
    const float* U1 = (const float*)d_in[4];
    const float* W2 = (const float*)d_in[5];
    const float* b2 = (const float*)d_in[6];
    const float* U2 = (const float*)d_in[7];
    float* ws  = (float*)d_ws;
    float* out = (float*)d_out;

    ka_gram<<<dim3(B_, NG), 256, 0, stream>>>(x1, x2, W1, b1, W2, b2, ws);
    kf_cet<<<dim3(B_, 2), 512, 0, stream>>>(U1, U2, ws, out);
    ke_out<<<dim3(B_, 16), 256, 0, stream>>>(x1, x2, ws, out);
}